// Round 1
// baseline (101.998 us; speedup 1.0000x reference)
//
#include <hip/hip_runtime.h>

#define BS 64
#define MA 64
#define H  64
#define NH 4

#define PJSTR 272   // P j-stride (floats): [j][n][h], n-stride 68, 16B aligned
#define PNSTR 68
#define CSTR  72    // c row stride (floats), 16B aligned, 72%32=8 -> jq lanes spread banks
#define CS_STR 260  // cs row stride
#define P_ELEMS (64 * PJSTR)  // 17408 floats
#define C_ELEMS (64 * CSTR)   // 4608 floats

__global__ __launch_bounds__(256) void atom_attn_kernel(
    const float* __restrict__ inputs,
    const int*   __restrict__ scope,
    const float* __restrict__ Wa_pair,
    const float* __restrict__ Wa_score,
    const float* __restrict__ W_proj,
    float* __restrict__ out_mol,    // [64][64]
    float* __restrict__ out_flat)   // [N+1][64]
{
    // LDS: Pbuf serves 3 lives: Wa_pair stage -> P[j][n][h] -> jq-partials -> W_proj stage.
    //      cbuf serves 2 lives: c rows -> cs[i_l][h*4+n].
    __shared__ __align__(16) float Pbuf[P_ELEMS];   // 69632 B
    __shared__ __align__(16) float cbuf[C_ELEMS];   // 18432 B
    __shared__ float wsbuf[H * NH];                 // 1024 B   (total ~89 KB -> 1 block/CU)

    const int t  = threadIdx.x;
    const int b  = blockIdx.y;
    const int i_base = blockIdx.x * 16;

    // ---- Phase A: stage Wa_score, c rows (all 64 slots), Wa_pair ----
    wsbuf[t] = Wa_score[t];
    {
        const int i = t >> 2, p = t & 3;
        const int r = scope[b * MA + i];
        const float4* src = (const float4*)(inputs + (size_t)r * H + p * 16);
        float4* dst = (float4*)(cbuf + i * CSTR + p * 16);
        dst[0] = src[0]; dst[1] = src[1]; dst[2] = src[2]; dst[3] = src[3];
    }
    {
        const float4* wg = (const float4*)Wa_pair;   // 64*256 floats = 4096 float4
        float4* wl = (float4*)Pbuf;
        #pragma unroll
        for (int k = 0; k < 16; ++k) wl[k * 256 + t] = wg[k * 256 + t];
    }
    __syncthreads();

    // ---- Phase P: P[i][c] = sum_h c[i][h] * Wa[h][c]  (c = h'*4 + n) ----
    // thread: cg = t&31 -> columns {cg + 32k}, ig = t>>5 -> rows [ig*8, ig*8+8)
    float pacc[8][8];
    #pragma unroll
    for (int a = 0; a < 8; ++a)
        #pragma unroll
        for (int k = 0; k < 8; ++k) pacc[a][k] = 0.f;
    {
        const int cg = t & 31, ig = t >> 5;
        for (int h = 0; h < 64; ++h) {
            float wv[8];
            #pragma unroll
            for (int k = 0; k < 8; ++k) wv[k] = Pbuf[h * 256 + cg + 32 * k];
            #pragma unroll
            for (int is = 0; is < 8; ++is) {
                const float cv = cbuf[(ig * 8 + is) * CSTR + h];
                #pragma unroll
                for (int k = 0; k < 8; ++k) pacc[is][k] += cv * wv[k];
            }
        }
        __syncthreads();  // all Wa reads done before overwriting Pbuf with P
        #pragma unroll
        for (int is = 0; is < 8; ++is)
            #pragma unroll
            for (int k = 0; k < 8; ++k) {
                const int c = cg + 32 * k;
                Pbuf[(ig * 8 + is) * PJSTR + (c & 3) * PNSTR + (c >> 2)] = pacc[is][k];
            }
    }
    __syncthreads();

    // ---- Phase B: scores + c_sum. thread = (i_l, n, jq); j = jq + 4*jj ----
    const int il = t >> 4, n = (t >> 2) & 3, jq = t & 3;
    float piR[64], wsr[64], acc[64];
    {
        const float* Pi = Pbuf + (i_base + il) * PJSTR + n * PNSTR;
        #pragma unroll
        for (int h = 0; h < 64; ++h) piR[h] = Pi[h];
        #pragma unroll
        for (int h = 0; h < 64; ++h) wsr[h] = wsbuf[h * 4 + n];
        #pragma unroll
        for (int h = 0; h < 64; ++h) acc[h] = 0.f;
    }
    for (int jj = 0; jj < 16; ++jj) {
        const int j = jq + 4 * jj;
        const float* Pj = Pbuf + j * PJSTR + n * PNSTR;
        const float* cj = cbuf + j * CSTR;
        float s = 0.f;
        #pragma unroll
        for (int h = 0; h < 64; ++h) s += fmaxf(piR[h] + Pj[h], 0.f) * wsr[h];
        const float a = 1.f / (1.f + __expf(-s));
        #pragma unroll
        for (int h = 0; h < 64; ++h) acc[h] += a * cj[h];
    }
    __syncthreads();  // P dead; write jq-partials into Pbuf
    {
        float* red = Pbuf + t * PNSTR;   // row index t == il*16 + n*4 + jq
        #pragma unroll
        for (int h = 0; h < 64; ++h) red[h] = acc[h];
    }
    __syncthreads();

    // ---- Reduce over jq -> cs[i_l][h*4+n] in cbuf (c rows dead) ----
    {
        const int il2 = t >> 4, n2 = (t >> 2) & 3, hq = t & 3;
        #pragma unroll
        for (int k = 0; k < 16; ++k) {
            const int h = hq * 16 + k;
            float v = 0.f;
            #pragma unroll
            for (int q = 0; q < 4; ++q)
                v += Pbuf[(il2 * 16 + n2 * 4 + q) * PNSTR + h];
            cbuf[il2 * CS_STR + h * 4 + n2] = v;
        }
    }
    __syncthreads();

    // ---- Phase C: out[i][o] = sum_c cs[i][c] * Wp[c][o]; Wp staged over dead Pbuf ----
    {
        const float4* wg = (const float4*)W_proj;    // 256*64 floats
        float4* wl = (float4*)Pbuf;
        #pragma unroll
        for (int k = 0; k < 16; ++k) wl[k * 256 + t] = wg[k * 256 + t];
    }
    __syncthreads();

    const int il3 = t >> 4, og = t & 15;
    float4 o4 = make_float4(0.f, 0.f, 0.f, 0.f);
    #pragma unroll 8
    for (int c = 0; c < 256; ++c) {
        const float cv = cbuf[il3 * CS_STR + c];
        const float4 wv = *(const float4*)(Pbuf + c * 64 + og * 4);
        o4.x += cv * wv.x; o4.y += cv * wv.y; o4.z += cv * wv.z; o4.w += cv * wv.w;
    }
    // scatter to flat (row index IS scope[b][i]; pads r==0 skip, row 0 stays memset-zero)
    {
        const int r = scope[b * MA + i_base + il3];
        if (r > 0) *(float4*)(out_flat + (size_t)r * H + og * 4) = o4;
    }
    // c_mol: reduce over i within wave (lanes xor 16,32), then atomicAdd (4 waves x 4 i-blocks)
    o4.x += __shfl_xor(o4.x, 16, 64); o4.y += __shfl_xor(o4.y, 16, 64);
    o4.z += __shfl_xor(o4.z, 16, 64); o4.w += __shfl_xor(o4.w, 16, 64);
    o4.x += __shfl_xor(o4.x, 32, 64); o4.y += __shfl_xor(o4.y, 32, 64);
    o4.z += __shfl_xor(o4.z, 32, 64); o4.w += __shfl_xor(o4.w, 32, 64);
    if ((t & 63) < 16) {
        float* m = out_mol + b * H + og * 4;
        atomicAdd(m + 0, o4.x); atomicAdd(m + 1, o4.y);
        atomicAdd(m + 2, o4.z); atomicAdd(m + 3, o4.w);
    }
}

extern "C" void kernel_launch(void* const* d_in, const int* in_sizes, int n_in,
                              void* d_out, int out_size, void* d_ws, size_t ws_size,
                              hipStream_t stream) {
    const float* inputs   = (const float*)d_in[0];
    const int*   scope    = (const int*)d_in[1];
    // d_in[2] = scope_rev (unused: flat row index == scope value)
    const float* Wa_pair  = (const float*)d_in[3];
    const float* Wa_score = (const float*)d_in[4];
    const float* W_proj   = (const float*)d_in[5];
    float* out = (float*)d_out;

    // zero c_mol region (atomic-accumulated) + flat row 0 (+ pad safety)
    hipMemsetAsync(d_out, 0, (size_t)out_size * sizeof(float), stream);

    dim3 grid(4, BS);  // (i-quarter, molecule): 256 blocks = 1/CU
    atom_attn_kernel<<<grid, 256, 0, stream>>>(inputs, scope, Wa_pair, Wa_score,
                                               W_proj, out, out + BS * H);
}

// Round 2
// 78.501 us; speedup vs baseline: 1.2993x; 1.2993x over previous
//
#include <hip/hip_runtime.h>
#include <stdint.h>

#define BSZ 64
#define MA 64
#define HD 64
#define NHD 4

using f32x4  = __attribute__((ext_vector_type(4))) float;
using bf16x8 = __attribute__((ext_vector_type(8))) __bf16;
using us8    = __attribute__((ext_vector_type(8))) unsigned short;

// LDS strides (elements). All b128-read strides are 16B-multiples.
#define WA_STR 260   // Wa_bf16 [64][WA_STR] ushort   (row-major [h][c], u16 frag reads)
#define P_STR   68   // P_f32   [4][64][P_STR] float  (272B rows, 16B aligned)
#define WP_STR  68   // Wp_bf16 [256][WP_STR] ushort  (row-major [c][o], u16 frag reads)
#define CB_STR  72   // cb_bf16 [64 j][CB_STR h]      (A for P-mfma, 144B rows)
#define CT_STR  72   // cbT     [64 h][CT_STR j]      (B for acc-mfma)
#define AB_STR  72   // a_bf16  [64 m][AB_STR j]      (A for acc-mfma, m = i*4+n)
#define CS_STR 264   // cs_bf16 [16 i][CS_STR c]      (A for proj-mfma, 528B rows)

__device__ __forceinline__ unsigned short f2bf(float f) {
    union { float f; uint32_t u; } v; v.f = f;
    uint32_t u = v.u + 0x7fffu + ((v.u >> 16) & 1u);
    return (unsigned short)(u >> 16);
}

__global__ __launch_bounds__(512, 2) void atom_attn(
    const float* __restrict__ inputs,
    const int*   __restrict__ scope,
    const float* __restrict__ Wa_pair,
    const float* __restrict__ Wa_score,
    const float* __restrict__ W_proj,
    float* __restrict__ out_mol,    // [64][64]
    float* __restrict__ out_flat)   // [N+1][64]
{
    // big region: Wa_bf16 (33.3KB) -> P_f32 (69.6KB) -> Wp_bf16 (34.8KB)
    __shared__ __align__(16) unsigned char s_big[4 * 64 * P_STR * 4];
    __shared__ __align__(16) unsigned short s_cb[64 * CB_STR];
    __shared__ __align__(16) unsigned short s_ct[64 * CT_STR];
    __shared__ __align__(16) unsigned short s_ab[64 * AB_STR];
    __shared__ __align__(16) unsigned short s_cs[16 * CS_STR];
    __shared__ __align__(16) float s_ws[4 * 64];

    unsigned short* sWa = (unsigned short*)s_big;
    float*          sP  = (float*)s_big;
    unsigned short* sWp = (unsigned short*)s_big;

    const int t = threadIdx.x;
    const int w = t >> 6, l = t & 63;
    const int b = blockIdx.y, i_base = blockIdx.x * 16;
    const int ml = l & 15, q = l >> 4;

    // ---------------- Phase 0: stage c (bf16, 2 layouts), Wa (bf16), ws (transposed) ----------------
    if (t < 256) s_ws[(t & 3) * 64 + (t >> 2)] = Wa_score[t];
    {
        const int j = t >> 3, p = t & 7;
        const int r = scope[b * MA + j];
        const float4 v0 = *(const float4*)(inputs + (size_t)r * HD + p * 8);
        const float4 v1 = *(const float4*)(inputs + (size_t)r * HD + p * 8 + 4);
        us8 uv;
        uv[0] = f2bf(v0.x); uv[1] = f2bf(v0.y); uv[2] = f2bf(v0.z); uv[3] = f2bf(v0.w);
        uv[4] = f2bf(v1.x); uv[5] = f2bf(v1.y); uv[6] = f2bf(v1.z); uv[7] = f2bf(v1.w);
        *(us8*)&s_cb[j * CB_STR + p * 8] = uv;
        #pragma unroll
        for (int e = 0; e < 8; ++e) s_ct[(p * 8 + e) * CT_STR + j] = uv[e];
    }
    {
        const int h = t >> 3, cseg = t & 7;
        #pragma unroll
        for (int qq = 0; qq < 8; ++qq) {
            const int c0 = cseg * 32 + qq * 4;
            const float4 v = *(const float4*)(Wa_pair + h * 256 + c0);
            ushort4 pk; pk.x = f2bf(v.x); pk.y = f2bf(v.y); pk.z = f2bf(v.z); pk.w = f2bf(v.w);
            *(ushort4*)&sWa[h * WA_STR + c0] = pk;
        }
    }
    __syncthreads();

    // ---------------- Phase 1: P = c @ Wa  (M=64 j, N=256 c, K=64 h), wave w owns cols [w*32, w*32+32) ----
    f32x4 pacc[4][2];
    {
        #pragma unroll
        for (int mt = 0; mt < 4; ++mt)
            #pragma unroll
            for (int nx = 0; nx < 2; ++nx) pacc[mt][nx] = f32x4{0.f, 0.f, 0.f, 0.f};
        bf16x8 afr[4][2];
        #pragma unroll
        for (int mt = 0; mt < 4; ++mt)
            #pragma unroll
            for (int ks = 0; ks < 2; ++ks)
                afr[mt][ks] = __builtin_bit_cast(bf16x8,
                    *(const us8*)&s_cb[(mt * 16 + ml) * CB_STR + ks * 32 + q * 8]);
        bf16x8 bfr[2][2];
        #pragma unroll
        for (int nx = 0; nx < 2; ++nx)
            #pragma unroll
            for (int ks = 0; ks < 2; ++ks) {
                const int c = (2 * w + nx) * 16 + ml;
                us8 uv;
                #pragma unroll
                for (int e = 0; e < 8; ++e) uv[e] = sWa[(ks * 32 + q * 8 + e) * WA_STR + c];
                bfr[nx][ks] = __builtin_bit_cast(bf16x8, uv);
            }
        #pragma unroll
        for (int mt = 0; mt < 4; ++mt)
            #pragma unroll
            for (int nx = 0; nx < 2; ++nx)
                #pragma unroll
                for (int ks = 0; ks < 2; ++ks)
                    pacc[mt][nx] = __builtin_amdgcn_mfma_f32_16x16x32_bf16(
                        afr[mt][ks], bfr[nx][ks], pacc[mt][nx], 0, 0, 0);
    }
    __syncthreads();   // all Wa reads done before P overwrites the region
    {
        // D: col = lane&15, row = (lane>>4)*4 + r.  Store P as [n][j][h'] fp32, c = h'*4+n
        #pragma unroll
        for (int mt = 0; mt < 4; ++mt)
            #pragma unroll
            for (int nx = 0; nx < 2; ++nx) {
                const int c = (2 * w + nx) * 16 + ml;
                const int n = c & 3, hp = c >> 2;
                #pragma unroll
                for (int r = 0; r < 4; ++r) {
                    const int row = mt * 16 + q * 4 + r;
                    sP[(n * 64 + row) * P_STR + hp] = pacc[mt][nx][r];
                }
            }
    }
    __syncthreads();

    // ---------------- Phase 2: scores. wave = (n, i-half); lane = j ----------------
    {
        const int n = w & 3, ih = w >> 2;
        float pj[64], wsr[64];
        #pragma unroll
        for (int k = 0; k < 16; ++k)
            *(f32x4*)&pj[k * 4] = *(const f32x4*)&sP[(n * 64 + l) * P_STR + k * 4];
        #pragma unroll
        for (int k = 0; k < 16; ++k)
            *(f32x4*)&wsr[k * 4] = *(const f32x4*)&s_ws[n * 64 + k * 4];
        #pragma unroll
        for (int ii = 0; ii < 8; ++ii) {
            const int iloc = ih * 8 + ii;
            const float* Prow = &sP[(n * 64 + (i_base + iloc)) * P_STR];
            float s = 0.f;
            #pragma unroll
            for (int hc = 0; hc < 4; ++hc) {
                float pi[16];
                *(f32x4*)&pi[0]  = *(const f32x4*)&Prow[hc * 16];
                *(f32x4*)&pi[4]  = *(const f32x4*)&Prow[hc * 16 + 4];
                *(f32x4*)&pi[8]  = *(const f32x4*)&Prow[hc * 16 + 8];
                *(f32x4*)&pi[12] = *(const f32x4*)&Prow[hc * 16 + 12];
                #pragma unroll
                for (int e = 0; e < 16; ++e)
                    s += wsr[hc * 16 + e] * fmaxf(pi[e] + pj[hc * 16 + e], 0.f);
            }
            const float a = 1.f / (1.f + __expf(-s));
            s_ab[(iloc * 4 + n) * AB_STR + l] = f2bf(a);   // A-layout for acc-mfma: m = iloc*4+n, k = j
        }
    }
    __syncthreads();

    // ---------------- Phase 3: c_sum = A @ c (M=64 m=(i,n), N=64 h, K=64 j) + stage Wp ----------------
    {
        const int mt = w >> 1;
        bf16x8 afr[2];
        #pragma unroll
        for (int ks = 0; ks < 2; ++ks)
            afr[ks] = __builtin_bit_cast(bf16x8,
                *(const us8*)&s_ab[(mt * 16 + ml) * AB_STR + ks * 32 + q * 8]);
        #pragma unroll
        for (int nx = 0; nx < 2; ++nx) {
            const int nt = (w & 1) * 2 + nx;
            f32x4 dacc = f32x4{0.f, 0.f, 0.f, 0.f};
            #pragma unroll
            for (int ks = 0; ks < 2; ++ks) {
                bf16x8 bfr = __builtin_bit_cast(bf16x8,
                    *(const us8*)&s_ct[(nt * 16 + ml) * CT_STR + ks * 32 + q * 8]);
                dacc = __builtin_amdgcn_mfma_f32_16x16x32_bf16(afr[ks], bfr, dacc, 0, 0, 0);
            }
            const int h = nt * 16 + ml;
            #pragma unroll
            for (int r = 0; r < 4; ++r) {
                const int m = mt * 16 + q * 4 + r;
                s_cs[(m >> 2) * CS_STR + h * 4 + (m & 3)] = f2bf(dacc[r]);  // cs[i][h*4+n]
            }
        }
    }
    {   // stage Wp over dead P region (score consumed P; barrier above)
        const int k = t >> 1, seg = t & 1;
        #pragma unroll
        for (int qq = 0; qq < 8; ++qq) {
            const int o0 = seg * 32 + qq * 4;
            const float4 v = *(const float4*)(W_proj + k * 64 + o0);
            ushort4 pk; pk.x = f2bf(v.x); pk.y = f2bf(v.y); pk.z = f2bf(v.z); pk.w = f2bf(v.w);
            *(ushort4*)&sWp[k * WP_STR + o0] = pk;
        }
    }
    __syncthreads();

    // ---------------- Phase 4: out = cs @ Wp (M=16 i, N=64 o, K=256 c), waves 0-3 ----------------
    if (w < 4) {
        f32x4 dc = f32x4{0.f, 0.f, 0.f, 0.f};
        #pragma unroll
        for (int ks = 0; ks < 8; ++ks) {
            bf16x8 af = __builtin_bit_cast(bf16x8,
                *(const us8*)&s_cs[ml * CS_STR + ks * 32 + q * 8]);
            us8 uv;
            #pragma unroll
            for (int e = 0; e < 8; ++e) uv[e] = sWp[(ks * 32 + q * 8 + e) * WP_STR + w * 16 + ml];
            bf16x8 bf = __builtin_bit_cast(bf16x8, uv);
            dc = __builtin_amdgcn_mfma_f32_16x16x32_bf16(af, bf, dc, 0, 0, 0);
        }
        const int o = w * 16 + ml;
        #pragma unroll
        for (int r = 0; r < 4; ++r) {
            const int iloc = q * 4 + r;
            const int row = scope[b * MA + i_base + iloc];
            if (row > 0) out_flat[(size_t)row * HD + o] = dc[r];
        }
        float s4 = dc[0] + dc[1] + dc[2] + dc[3];
        s4 += __shfl_xor(s4, 16, 64);
        s4 += __shfl_xor(s4, 32, 64);
        if (l < 16) atomicAdd(out_mol + b * HD + o, s4);
    }
}

extern "C" void kernel_launch(void* const* d_in, const int* in_sizes, int n_in,
                              void* d_out, int out_size, void* d_ws, size_t ws_size,
                              hipStream_t stream) {
    const float* inputs   = (const float*)d_in[0];
    const int*   scope    = (const int*)d_in[1];
    // d_in[2] = scope_rev (unused: flat row index == scope value)
    const float* Wa_pair  = (const float*)d_in[3];
    const float* Wa_score = (const float*)d_in[4];
    const float* W_proj   = (const float*)d_in[5];
    float* out = (float*)d_out;

    // zero c_mol (atomic-accumulated) + flat row 0
    hipMemsetAsync(d_out, 0, (size_t)out_size * sizeof(float), stream);

    dim3 grid(4, BSZ);   // (i-quarter, molecule): 256 blocks, 512 threads = 8 waves/CU
    atom_attn<<<grid, 512, 0, stream>>>(inputs, scope, Wa_pair, Wa_score,
                                        W_proj, out, out + BSZ * HD);
}

// Round 4
// 75.997 us; speedup vs baseline: 1.3421x; 1.0329x over previous
//
#include <hip/hip_runtime.h>
#include <stdint.h>

typedef _Float16 h2 __attribute__((ext_vector_type(2)));
typedef _Float16 h8 __attribute__((ext_vector_type(8)));
typedef float f32x4 __attribute__((ext_vector_type(4)));
typedef unsigned int u32;
typedef unsigned short u16;

// LDS strides (in elements of the buffer's type)
#define WT_STR 68    // WaT  [c'=256][h]   u16 ; 136B rows (b64-aligned)
#define PJ_STR 68    // pjT  [n*64+j][h]   u16 ; 136B rows
#define WP_STR 268   // WpT  [o=64][c2]    u16 ; 536B rows (b64-aligned)
#define PI_STR 36    // sPi  [n][i<8][h2]  u32 ; 144B rows (b128-aligned)
#define CB_STR 72    // cb   [j=64][h]     u16 ; 144B rows (b128-aligned)
#define CT_STR 68    // ct   [h=64][j]     u16 ; 136B rows
#define AB_STR 72    // ab   [m=32][j]     u16 ; 144B rows
#define CS_STR 264   // cs   [i=16][c2]    u16 ; 528B rows (b128-aligned)
#define WS_STR 36    // ws   [n=4][h2]     u32 ; 144B rows

__device__ __forceinline__ u32 pk2(float a, float b) {
    return __builtin_bit_cast(u32, __builtin_amdgcn_cvt_pkrtz(a, b));
}
__device__ __forceinline__ h8 frag4(u32 a, u32 b, u32 c, u32 d) {
    return __builtin_bit_cast(h8, make_uint4(a, b, c, d));
}

__global__ __launch_bounds__(256, 2) void atom_attn(
    const float* __restrict__ inputs,
    const int*   __restrict__ scope,
    const float* __restrict__ Wa_pair,
    const float* __restrict__ Wa_score,
    const float* __restrict__ W_proj,
    float* __restrict__ out_mol,    // [64][64]
    float* __restrict__ out_flat)   // [N+1][64]
{
    // s_big lives 3 lives: WaT -> pjT -> WpT
    __shared__ __align__(16) u16 s_big[256 * WT_STR];        // 34,816 B
    __shared__ __align__(16) u32 s_pi[4 * 8 * PI_STR];       //  4,608 B
    __shared__ __align__(16) u16 s_cbcs[64 * CB_STR];        //  9,216 B (cb -> cs)
    __shared__ __align__(16) u16 s_ct[64 * CT_STR];          //  8,704 B
    __shared__ __align__(16) u16 s_ab[32 * AB_STR];          //  4,608 B
    __shared__ __align__(16) u32 s_ws[4 * WS_STR];           //    576 B

    const int t = threadIdx.x;
    const int w = t >> 6, l = t & 63;
    const int ml = l & 15, q = l >> 4;
    const int b = blockIdx.y, bx = blockIdx.x;
    const int i_base = bx * 8;

    // ================= Phase 0: stage ws, c (cb + ct), WaT =================
    if (t < 128) {  // ws transposed+packed: s_ws[n][h2] = (ws[2h2,n], ws[2h2+1,n])
        const int n = t & 3, hh = t >> 2;
        const float g0 = Wa_score[(2 * hh) * 4 + n];
        const float g1 = Wa_score[(2 * hh + 1) * 4 + n];
        s_ws[n * WS_STR + hh] = pk2(g0, g1);
    }
    {   // c rows -> cb [j][h] (h-packed) and ct [h][j] (j-pair packed)
        const int jp = (t & 31) * 2;
        const int pp = t >> 5;           // h-octant 0..7
        const int r0 = scope[b * 64 + jp];
        const int r1 = scope[b * 64 + jp + 1];
        const f32x4 a0 = *(const f32x4*)(inputs + (size_t)r0 * 64 + pp * 8);
        const f32x4 a1 = *(const f32x4*)(inputs + (size_t)r0 * 64 + pp * 8 + 4);
        const f32x4 b0 = *(const f32x4*)(inputs + (size_t)r1 * 64 + pp * 8);
        const f32x4 b1 = *(const f32x4*)(inputs + (size_t)r1 * 64 + pp * 8 + 4);
        float A[8] = {a0[0], a0[1], a0[2], a0[3], a1[0], a1[1], a1[2], a1[3]};
        float B[8] = {b0[0], b0[1], b0[2], b0[3], b1[0], b1[1], b1[2], b1[3]};
        *(uint4*)&s_cbcs[jp * CB_STR + pp * 8] =
            make_uint4(pk2(A[0], A[1]), pk2(A[2], A[3]), pk2(A[4], A[5]), pk2(A[6], A[7]));
        *(uint4*)&s_cbcs[(jp + 1) * CB_STR + pp * 8] =
            make_uint4(pk2(B[0], B[1]), pk2(B[2], B[3]), pk2(B[4], B[5]), pk2(B[6], B[7]));
        #pragma unroll
        for (int e = 0; e < 8; ++e)
            *(u32*)&s_ct[(pp * 8 + e) * CT_STR + jp] = pk2(A[e], B[e]);
    }
    {   // WaT[c'][h] f16, c' = (c&3)*64 + (c>>2)  (n-major column permutation)
        const int cg = (t & 127) * 2;        // even global column
        const int hh2 = t >> 7;              // h half
        const int cp0 = (cg & 3) * 64 + (cg >> 2);   // dest row for cg; cg+1 -> +64
        #pragma unroll
        for (int k2 = 0; k2 < 16; ++k2) {
            const int h0 = hh2 * 32 + k2 * 2;
            const float2 r0 = *(const float2*)(Wa_pair + h0 * 256 + cg);
            const float2 r1 = *(const float2*)(Wa_pair + (h0 + 1) * 256 + cg);
            *(u32*)&s_big[cp0 * WT_STR + h0]        = pk2(r0.x, r1.x);
            *(u32*)&s_big[(cp0 + 64) * WT_STR + h0] = pk2(r0.y, r1.y);
        }
    }
    __syncthreads();

    // ================= Phase 1: D = P^T  (M=c'=256, N=j=64, K=h=64) =================
    // wave: mh = w&1 -> mt in [mh*8, mh*8+8); jp2 = w>>1 -> j-tiles {2*jp2, 2*jp2+1}
    const int mh = w & 1, jp2 = w >> 1;
    f32x4 D[8][2];
    #pragma unroll
    for (int k = 0; k < 8; ++k) { D[k][0] = (f32x4)0.f; D[k][1] = (f32x4)0.f; }
    {
        h8 bf[2][2];
        #pragma unroll
        for (int jt = 0; jt < 2; ++jt)
            #pragma unroll
            for (int ks = 0; ks < 2; ++ks)
                bf[jt][ks] = __builtin_bit_cast(h8,
                    *(const uint4*)&s_cbcs[((jp2 * 2 + jt) * 16 + ml) * CB_STR + ks * 32 + q * 8]);
        #pragma unroll
        for (int k = 0; k < 8; ++k) {
            const int mt = mh * 8 + k;
            #pragma unroll
            for (int ks = 0; ks < 2; ++ks) {
                const uint2 x0 = *(const uint2*)&s_big[(mt * 16 + ml) * WT_STR + ks * 32 + q * 8];
                const uint2 x1 = *(const uint2*)&s_big[(mt * 16 + ml) * WT_STR + ks * 32 + q * 8 + 4];
                const h8 af = frag4(x0.x, x0.y, x1.x, x1.y);
                D[k][0] = __builtin_amdgcn_mfma_f32_16x16x32_f16(af, bf[0][ks], D[k][0], 0, 0, 0);
                D[k][1] = __builtin_amdgcn_mfma_f32_16x16x32_f16(af, bf[1][ks], D[k][1], 0, 0, 0);
            }
        }
    }
    __syncthreads();   // WaT reads done -> pjT/sPi may overwrite s_big
    {
        const int wt = bx >> 1, mlo = (bx & 1) * 8;
        #pragma unroll
        for (int k = 0; k < 8; ++k) {
            const int mt = mh * 8 + k;
            const int nb = mt >> 2, h0 = (mt & 3) * 16 + q * 4;
            #pragma unroll
            for (int jt = 0; jt < 2; ++jt) {
                const int jtile = jp2 * 2 + jt;
                const int j = jtile * 16 + ml;
                const u32 p0 = pk2(D[k][jt][0], D[k][jt][1]);
                const u32 p1 = pk2(D[k][jt][2], D[k][jt][3]);
                *(uint2*)&s_big[(nb * 64 + j) * PJ_STR + h0] = make_uint2(p0, p1);
                if (jtile == wt && ml >= mlo && ml < mlo + 8)
                    *(uint2*)&s_pi[(nb * 8 + (ml - mlo)) * PI_STR + (h0 >> 1)] = make_uint2(p0, p1);
            }
        }
    }
    __syncthreads();

    // ================= Phase 2: scores (wave = n, lane = j) =================
    {
        const int n = w;
        u32 pj_u[32];
        #pragma unroll
        for (int k = 0; k < 16; ++k) {
            const uint2 v = *(const uint2*)&s_big[(n * 64 + l) * PJ_STR + k * 4];
            pj_u[2 * k] = v.x; pj_u[2 * k + 1] = v.y;
        }
        u32 ws_u[32];
        #pragma unroll
        for (int k = 0; k < 8; ++k) {
            const uint4 v = *(const uint4*)&s_ws[n * WS_STR + k * 4];
            ws_u[4 * k] = v.x; ws_u[4 * k + 1] = v.y; ws_u[4 * k + 2] = v.z; ws_u[4 * k + 3] = v.w;
        }
        const h2 zero2 = {(_Float16)0.f, (_Float16)0.f};
        #pragma unroll
        for (int ii = 0; ii < 8; ++ii) {
            const u32* pir = &s_pi[(n * 8 + ii) * PI_STR];
            float s0 = 0.f, s1 = 0.f;
            #pragma unroll
            for (int c8 = 0; c8 < 8; ++c8) {
                const uint4 pv = *(const uint4*)&pir[c8 * 4];
                const u32 pe[4] = {pv.x, pv.y, pv.z, pv.w};
                #pragma unroll
                for (int e = 0; e < 4; ++e) {
                    const h2 pi2 = __builtin_bit_cast(h2, pe[e]);
                    const h2 pj2 = __builtin_bit_cast(h2, pj_u[c8 * 4 + e]);
                    h2 tv = pi2 + pj2;                       // v_pk_add_f16
                    tv = __builtin_elementwise_max(tv, zero2); // v_pk_max_f16
                    if (e & 1)
                        s1 = __builtin_amdgcn_fdot2(tv,
                                __builtin_bit_cast(h2, ws_u[c8 * 4 + e]), s1, false);
                    else
                        s0 = __builtin_amdgcn_fdot2(tv,
                                __builtin_bit_cast(h2, ws_u[c8 * 4 + e]), s0, false);
                }
            }
            const float s = s0 + s1;
            const float a = 1.f / (1.f + __expf(-s));
            const _Float16 ah = (_Float16)a;
            s_ab[(ii * 4 + n) * AB_STR + l] = __builtin_bit_cast(u16, ah);
        }
    }
    __syncthreads();   // ab written; pjT dead -> WpT may overwrite s_big

    // ================= Phase 3: c_sum = ab @ c (M=32, N=64 h, K=64 j) + stage WpT =================
    {   // stage WpT[o][c2] f16 (overwrites pjT region)
        const int o0 = (t & 31) * 2, seg = t >> 5;
        #pragma unroll
        for (int k2 = 0; k2 < 16; ++k2) {
            const int c0 = seg * 32 + k2 * 2;
            const float2 r0 = *(const float2*)(W_proj + c0 * 64 + o0);
            const float2 r1 = *(const float2*)(W_proj + (c0 + 1) * 64 + o0);
            *(u32*)&s_big[o0 * WP_STR + c0]       = pk2(r0.x, r1.x);
            *(u32*)&s_big[(o0 + 1) * WP_STR + c0] = pk2(r0.y, r1.y);
        }
    }
    {
        h8 bfc[2];
        #pragma unroll
        for (int ks = 0; ks < 2; ++ks) {
            const uint2 y0 = *(const uint2*)&s_ct[(w * 16 + ml) * CT_STR + ks * 32 + q * 8];
            const uint2 y1 = *(const uint2*)&s_ct[(w * 16 + ml) * CT_STR + ks * 32 + q * 8 + 4];
            bfc[ks] = frag4(y0.x, y0.y, y1.x, y1.y);
        }
        f32x4 D2[2]; D2[0] = (f32x4)0.f; D2[1] = (f32x4)0.f;
        #pragma unroll
        for (int mt = 0; mt < 2; ++mt)
            #pragma unroll
            for (int ks = 0; ks < 2; ++ks) {
                const h8 af = __builtin_bit_cast(h8,
                    *(const uint4*)&s_ab[(mt * 16 + ml) * AB_STR + ks * 32 + q * 8]);
                D2[mt] = __builtin_amdgcn_mfma_f32_16x16x32_f16(af, bfc[ks], D2[mt], 0, 0, 0);
            }
        // D rows: m = mt*16 + q*4 + r -> iloc = mt*4+q, n = r; cs[iloc][h*4+n], h = w*16+ml
        #pragma unroll
        for (int mt = 0; mt < 2; ++mt) {
            const int iloc = mt * 4 + q, h = w * 16 + ml;
            *(uint2*)&s_cbcs[iloc * CS_STR + h * 4] =
                make_uint2(pk2(D2[mt][0], D2[mt][1]), pk2(D2[mt][2], D2[mt][3]));
        }
    }
    __syncthreads();

    // ================= Phase 4: out = cs @ Wp (M=16(8 valid), N=64 o, K=256) =================
    {
        f32x4 D4 = (f32x4)0.f;
        #pragma unroll
        for (int ks = 0; ks < 8; ++ks) {
            const h8 af = __builtin_bit_cast(h8,
                *(const uint4*)&s_cbcs[ml * CS_STR + ks * 32 + q * 8]);
            const uint2 z0 = *(const uint2*)&s_big[(w * 16 + ml) * WP_STR + ks * 32 + q * 8];
            const uint2 z1 = *(const uint2*)&s_big[(w * 16 + ml) * WP_STR + ks * 32 + q * 8 + 4];
            const h8 bf4 = frag4(z0.x, z0.y, z1.x, z1.y);
            D4 = __builtin_amdgcn_mfma_f32_16x16x32_f16(af, bf4, D4, 0, 0, 0);
        }
        const int o = w * 16 + ml;
        if (q < 2) {
            #pragma unroll
            for (int r = 0; r < 4; ++r) {
                const int iloc = q * 4 + r;
                const int row = scope[b * 64 + i_base + iloc];
                if (row > 0) out_flat[(size_t)row * 64 + o] = D4[r];
            }
        }
        float s4 = (q < 2) ? (D4[0] + D4[1] + D4[2] + D4[3]) : 0.f;
        s4 += __shfl_xor(s4, 16, 64);
        s4 += __shfl_xor(s4, 32, 64);
        if (l < 16) atomicAdd(out_mol + b * 64 + o, s4);
    }
}

extern "C" void kernel_launch(void* const* d_in, const int* in_sizes, int n_in,
                              void* d_out, int out_size, void* d_ws, size_t ws_size,
                              hipStream_t stream) {
    const float* inputs   = (const float*)d_in[0];
    const int*   scope    = (const int*)d_in[1];
    // d_in[2] = scope_rev (unused: flat row index == scope value)
    const float* Wa_pair  = (const float*)d_in[3];
    const float* Wa_score = (const float*)d_in[4];
    const float* W_proj   = (const float*)d_in[5];
    float* out = (float*)d_out;

    // zero only what isn't fully overwritten: out_mol [64*64] + flat row 0 [64]
    (void)hipMemsetAsync(d_out, 0, (64 * 64 + 64) * sizeof(float), stream);

    dim3 grid(8, 64);   // (i-octant, molecule): 512 blocks x 256 thr = 2 blocks/CU
    atom_attn<<<grid, 256, 0, stream>>>(inputs, scope, Wa_pair, Wa_score,
                                        W_proj, out, out + 64 * 64);
}

// Round 5
// 74.397 us; speedup vs baseline: 1.3710x; 1.0215x over previous
//
#include <hip/hip_runtime.h>
#include <stdint.h>

typedef _Float16 h2 __attribute__((ext_vector_type(2)));
typedef _Float16 h8 __attribute__((ext_vector_type(8)));
typedef float f32x4 __attribute__((ext_vector_type(4)));
typedef unsigned int u32;
typedef unsigned short u16;

// LDS strides (in elements of the buffer's type)
#define WT_STR 68    // WaT  [c'=256][h]   u16 ; 136B rows
#define PJ_STR 68    // pjT  [n*64+j][h]   u16 ; 136B rows
#define WP_STR 268   // WpT  [o=64][c2]    u16 ; 536B rows
#define PI_STR 36    // sPi  [n][i<16][h2] u32 ; 144B rows
#define CB_STR 72    // cb   [j=64][h]     u16 ; 144B rows
#define CT_STR 68    // ct   [h=64][j]     u16 ; 136B rows
#define AB_STR 72    // ab   [m=64][j]     u16 ; 144B rows
#define CS_STR 264   // cs   [i=16][c2]    u16 ; 528B rows
#define WS_STR 36    // ws   [n=4][h2]     u32 ; 144B rows

__device__ __forceinline__ u32 pk2(float a, float b) {
    return __builtin_bit_cast(u32, __builtin_amdgcn_cvt_pkrtz(a, b));
}
__device__ __forceinline__ h8 frag4(u32 a, u32 b, u32 c, u32 d) {
    return __builtin_bit_cast(h8, make_uint4(a, b, c, d));
}

__global__ __launch_bounds__(512, 1) void atom_attn(
    const float* __restrict__ inputs,
    const int*   __restrict__ scope,
    const float* __restrict__ Wa_pair,
    const float* __restrict__ Wa_score,
    const float* __restrict__ W_proj,
    float* __restrict__ out_mol,    // [64][64]
    float* __restrict__ out_flat)   // [N+1][64]
{
    // Separate buffers — no aliasing, no extra barriers. Total ~149 KB -> 1 block/CU.
    __shared__ __align__(16) u16 s_wa[256 * WT_STR];         // 34,816 B
    __shared__ __align__(16) u16 s_pj[256 * PJ_STR];         // 34,816 B
    __shared__ __align__(16) u16 s_wp[64 * WP_STR];          // 34,304 B
    __shared__ __align__(16) u32 s_pi[4 * 16 * PI_STR];      //  9,216 B
    __shared__ __align__(16) u16 s_cb[64 * CB_STR];          //  9,216 B
    __shared__ __align__(16) u16 s_ct[64 * CT_STR];          //  8,704 B
    __shared__ __align__(16) u16 s_ab[64 * AB_STR];          //  9,216 B
    __shared__ __align__(16) u16 s_cs[16 * CS_STR];          //  8,448 B
    __shared__ __align__(16) u32 s_ws[4 * WS_STR];           //    576 B

    const int t = threadIdx.x;
    const int w = t >> 6, l = t & 63;
    const int ml = l & 15, q = l >> 4;
    const int b = blockIdx.y, bx = blockIdx.x;
    const int i_base = bx * 16;

    // ================= Phase 0: stage everything (ws, c, WaT, WpT) =================
    if (t < 256) {
        if (t < 128) {  // ws transposed+packed: s_ws[n][h2] = (ws[2h2,n], ws[2h2+1,n])
            const int n = t & 3, hh = t >> 2;
            const float g0 = Wa_score[(2 * hh) * 4 + n];
            const float g1 = Wa_score[(2 * hh + 1) * 4 + n];
            s_ws[n * WS_STR + hh] = pk2(g0, g1);
        }
        {   // c rows -> cb [j][h] (h-packed) and ct [h][j] (j-pair packed)
            const int jp = (t & 31) * 2;
            const int pp = t >> 5;           // h-octant 0..7
            const int r0 = scope[b * 64 + jp];
            const int r1 = scope[b * 64 + jp + 1];
            const f32x4 a0 = *(const f32x4*)(inputs + (size_t)r0 * 64 + pp * 8);
            const f32x4 a1 = *(const f32x4*)(inputs + (size_t)r0 * 64 + pp * 8 + 4);
            const f32x4 b0 = *(const f32x4*)(inputs + (size_t)r1 * 64 + pp * 8);
            const f32x4 b1 = *(const f32x4*)(inputs + (size_t)r1 * 64 + pp * 8 + 4);
            float A[8] = {a0[0], a0[1], a0[2], a0[3], a1[0], a1[1], a1[2], a1[3]};
            float B[8] = {b0[0], b0[1], b0[2], b0[3], b1[0], b1[1], b1[2], b1[3]};
            *(uint4*)&s_cb[jp * CB_STR + pp * 8] =
                make_uint4(pk2(A[0], A[1]), pk2(A[2], A[3]), pk2(A[4], A[5]), pk2(A[6], A[7]));
            *(uint4*)&s_cb[(jp + 1) * CB_STR + pp * 8] =
                make_uint4(pk2(B[0], B[1]), pk2(B[2], B[3]), pk2(B[4], B[5]), pk2(B[6], B[7]));
            #pragma unroll
            for (int e = 0; e < 8; ++e)
                *(u32*)&s_ct[(pp * 8 + e) * CT_STR + jp] = pk2(A[e], B[e]);
        }
        {   // WpT[o][c2] f16
            const int o0 = (t & 31) * 2, seg = t >> 5;
            #pragma unroll
            for (int k2 = 0; k2 < 16; ++k2) {
                const int c0 = seg * 32 + k2 * 2;
                const float2 r0 = *(const float2*)(W_proj + c0 * 64 + o0);
                const float2 r1 = *(const float2*)(W_proj + (c0 + 1) * 64 + o0);
                *(u32*)&s_wp[o0 * WP_STR + c0]       = pk2(r0.x, r1.x);
                *(u32*)&s_wp[(o0 + 1) * WP_STR + c0] = pk2(r0.y, r1.y);
            }
        }
    } else {
        // WaT[c'][h] f16, c' = (c&3)*64 + (c>>2)  (n-major column permutation)
        const int t2 = t & 255;
        const int cg = (t2 & 127) * 2;       // even global column
        const int hh2 = t2 >> 7;             // h half
        const int cp0 = (cg & 3) * 64 + (cg >> 2);   // dest row for cg; cg+1 -> +64
        #pragma unroll
        for (int k2 = 0; k2 < 16; ++k2) {
            const int h0 = hh2 * 32 + k2 * 2;
            const float2 r0 = *(const float2*)(Wa_pair + h0 * 256 + cg);
            const float2 r1 = *(const float2*)(Wa_pair + (h0 + 1) * 256 + cg);
            *(u32*)&s_wa[cp0 * WT_STR + h0]        = pk2(r0.x, r1.x);
            *(u32*)&s_wa[(cp0 + 64) * WT_STR + h0] = pk2(r0.y, r1.y);
        }
    }
    __syncthreads();

    // ================= Phase 1: D = P^T (M=c'=256, N=j=64, K=h=64), 8 waves =================
    // wave: mq = w&3 -> mt in [mq*4, mq*4+4); jh = w>>2 -> j-tiles {2jh, 2jh+1}
    {
        const int mq = w & 3, jh = w >> 2;
        f32x4 D[4][2];
        #pragma unroll
        for (int k = 0; k < 4; ++k) { D[k][0] = (f32x4)0.f; D[k][1] = (f32x4)0.f; }
        h8 bf[2][2];
        #pragma unroll
        for (int jt = 0; jt < 2; ++jt)
            #pragma unroll
            for (int ks = 0; ks < 2; ++ks)
                bf[jt][ks] = __builtin_bit_cast(h8,
                    *(const uint4*)&s_cb[((jh * 2 + jt) * 16 + ml) * CB_STR + ks * 32 + q * 8]);
        #pragma unroll
        for (int k = 0; k < 4; ++k) {
            const int mt = mq * 4 + k;
            #pragma unroll
            for (int ks = 0; ks < 2; ++ks) {
                const uint2 x0 = *(const uint2*)&s_wa[(mt * 16 + ml) * WT_STR + ks * 32 + q * 8];
                const uint2 x1 = *(const uint2*)&s_wa[(mt * 16 + ml) * WT_STR + ks * 32 + q * 8 + 4];
                const h8 af = frag4(x0.x, x0.y, x1.x, x1.y);
                D[k][0] = __builtin_amdgcn_mfma_f32_16x16x32_f16(af, bf[0][ks], D[k][0], 0, 0, 0);
                D[k][1] = __builtin_amdgcn_mfma_f32_16x16x32_f16(af, bf[1][ks], D[k][1], 0, 0, 0);
            }
        }
        // store P^T (separate buffers -> no barrier needed before stores)
        #pragma unroll
        for (int k = 0; k < 4; ++k) {
            const int mt = mq * 4 + k;
            const int nb = mt >> 2, h0 = (mt & 3) * 16 + q * 4;
            #pragma unroll
            for (int jt = 0; jt < 2; ++jt) {
                const int jtile = jh * 2 + jt;
                const int j = jtile * 16 + ml;
                const u32 p0 = pk2(D[k][jt][0], D[k][jt][1]);
                const u32 p1 = pk2(D[k][jt][2], D[k][jt][3]);
                *(uint2*)&s_pj[(nb * 64 + j) * PJ_STR + h0] = make_uint2(p0, p1);
                if (jtile == bx)   // j == i_base + ml -> this block's P_i rows
                    *(uint2*)&s_pi[(nb * 16 + ml) * PI_STR + (h0 >> 1)] = make_uint2(p0, p1);
            }
        }
    }
    __syncthreads();

    // ================= Phase 2: scores (wave = (n, i-half), lane = j) =================
    {
        const int n = w & 3, ih = w >> 2;
        u32 pj_u[32];
        #pragma unroll
        for (int k = 0; k < 16; ++k) {
            const uint2 v = *(const uint2*)&s_pj[(n * 64 + l) * PJ_STR + k * 4];
            pj_u[2 * k] = v.x; pj_u[2 * k + 1] = v.y;
        }
        u32 ws_u[32];
        #pragma unroll
        for (int k = 0; k < 8; ++k) {
            const uint4 v = *(const uint4*)&s_ws[n * WS_STR + k * 4];
            ws_u[4 * k] = v.x; ws_u[4 * k + 1] = v.y; ws_u[4 * k + 2] = v.z; ws_u[4 * k + 3] = v.w;
        }
        const h2 zero2 = {(_Float16)0.f, (_Float16)0.f};
        #pragma unroll
        for (int ii = 0; ii < 8; ++ii) {
            const int iloc = ih * 8 + ii;
            const u32* pir = &s_pi[(n * 16 + iloc) * PI_STR];
            float s0 = 0.f, s1 = 0.f;
            #pragma unroll
            for (int c8 = 0; c8 < 8; ++c8) {
                const uint4 pv = *(const uint4*)&pir[c8 * 4];
                const u32 pe[4] = {pv.x, pv.y, pv.z, pv.w};
                #pragma unroll
                for (int e = 0; e < 4; ++e) {
                    const h2 pi2 = __builtin_bit_cast(h2, pe[e]);
                    const h2 pj2 = __builtin_bit_cast(h2, pj_u[c8 * 4 + e]);
                    h2 tv = pi2 + pj2;                         // v_pk_add_f16
                    tv = __builtin_elementwise_max(tv, zero2); // v_pk_max_f16
                    if (e & 1)
                        s1 = __builtin_amdgcn_fdot2(tv,
                                __builtin_bit_cast(h2, ws_u[c8 * 4 + e]), s1, false);
                    else
                        s0 = __builtin_amdgcn_fdot2(tv,
                                __builtin_bit_cast(h2, ws_u[c8 * 4 + e]), s0, false);
                }
            }
            const float s = s0 + s1;
            const float a = 1.f / (1.f + __expf(-s));
            const _Float16 ah = (_Float16)a;
            s_ab[(iloc * 4 + n) * AB_STR + l] = __builtin_bit_cast(u16, ah);
        }
    }
    __syncthreads();

    // ================= Phase 3: c_sum = ab @ c (M=64 m=(i,n), N=64 h, K=64 j) =================
    {
        const int mt3 = w & 3, nh = w >> 2;
        h8 af3[2];
        #pragma unroll
        for (int ks = 0; ks < 2; ++ks)
            af3[ks] = __builtin_bit_cast(h8,
                *(const uint4*)&s_ab[(mt3 * 16 + ml) * AB_STR + ks * 32 + q * 8]);
        #pragma unroll
        for (int nx = 0; nx < 2; ++nx) {
            const int nt = nh * 2 + nx;
            f32x4 D2 = (f32x4)0.f;
            #pragma unroll
            for (int ks = 0; ks < 2; ++ks) {
                const uint2 y0 = *(const uint2*)&s_ct[(nt * 16 + ml) * CT_STR + ks * 32 + q * 8];
                const uint2 y1 = *(const uint2*)&s_ct[(nt * 16 + ml) * CT_STR + ks * 32 + q * 8 + 4];
                const h8 bfc = frag4(y0.x, y0.y, y1.x, y1.y);
                D2 = __builtin_amdgcn_mfma_f32_16x16x32_f16(af3[ks], bfc, D2, 0, 0, 0);
            }
            // D rows: m = mt3*16 + q*4 + r -> iloc = mt3*4+q, n = r; cs[iloc][h*4+n]
            const int iloc = mt3 * 4 + q, h = nt * 16 + ml;
            *(uint2*)&s_cs[iloc * CS_STR + h * 4] =
                make_uint2(pk2(D2[0], D2[1]), pk2(D2[2], D2[3]));
        }
    }
    __syncthreads();

    // ================= Phase 4: out = cs @ Wp (M=16 i, N=64 o, K=256), waves 0-3 =================
    if (w < 4) {
        f32x4 D4 = (f32x4)0.f;
        #pragma unroll
        for (int ks = 0; ks < 8; ++ks) {
            const h8 af = __builtin_bit_cast(h8,
                *(const uint4*)&s_cs[ml * CS_STR + ks * 32 + q * 8]);
            const uint2 z0 = *(const uint2*)&s_wp[(w * 16 + ml) * WP_STR + ks * 32 + q * 8];
            const uint2 z1 = *(const uint2*)&s_wp[(w * 16 + ml) * WP_STR + ks * 32 + q * 8 + 4];
            const h8 bf4 = frag4(z0.x, z0.y, z1.x, z1.y);
            D4 = __builtin_amdgcn_mfma_f32_16x16x32_f16(af, bf4, D4, 0, 0, 0);
        }
        const int o = w * 16 + ml;
        #pragma unroll
        for (int r = 0; r < 4; ++r) {
            const int iloc = q * 4 + r;
            const int row = scope[b * 64 + i_base + iloc];
            if (row > 0) out_flat[(size_t)row * 64 + o] = D4[r];
        }
        float s4 = D4[0] + D4[1] + D4[2] + D4[3];
        s4 += __shfl_xor(s4, 16, 64);
        s4 += __shfl_xor(s4, 32, 64);
        if (l < 16) atomicAdd(out_mol + b * 64 + o, s4);
    }
}

extern "C" void kernel_launch(void* const* d_in, const int* in_sizes, int n_in,
                              void* d_out, int out_size, void* d_ws, size_t ws_size,
                              hipStream_t stream) {
    const float* inputs   = (const float*)d_in[0];
    const int*   scope    = (const int*)d_in[1];
    // d_in[2] = scope_rev (unused: flat row index == scope value)
    const float* Wa_pair  = (const float*)d_in[3];
    const float* Wa_score = (const float*)d_in[4];
    const float* W_proj   = (const float*)d_in[5];
    float* out = (float*)d_out;

    // zero only what isn't fully overwritten: out_mol [64*64] + flat row 0 [64]
    (void)hipMemsetAsync(d_out, 0, (64 * 64 + 64) * sizeof(float), stream);

    dim3 grid(4, 64);   // (i-16-group, molecule): 256 blocks x 512 thr = 1 block/CU, 8 waves
    atom_attn<<<grid, 512, 0, stream>>>(inputs, scope, Wa_pair, Wa_score,
                                        W_proj, out, out + 64 * 64);
}